// Round 2
// baseline (110.094 us; speedup 1.0000x reference)
//
#include <hip/hip_runtime.h>
#include <hip/hip_bf16.h>

typedef __attribute__((ext_vector_type(8))) short short8;
typedef __attribute__((ext_vector_type(4))) float float4_t;

#define NB 32
#define NL 256
#define NC 16
#define ND 128
#define OUT_PLANE (NB * ND * NL)   // 1048576 elements per stacked output plane

__device__ inline unsigned short f2bf(float f) {
    union { float f; unsigned int i; } c;
    c.f = f;
    unsigned int r = c.i + 0x7FFFu + ((c.i >> 16) & 1u);  // RN-even
    return (unsigned short)(r >> 16);
}

// ---------------------------------------------------------------------------
// Pre-permute fp32 conv weights [D,Din,3] into bf16 per-lane MFMA B-fragment
// order: frag[s][nt][lane][j], s=0..11 (k-step of 32), nt=0..7 (16-wide dout
// tile), lane=0..63, j=0..7.  B[k'][n]: n = lane&15, k' = s*32+(lane>>4)*8+j,
// tap t = s>>2, k = (s&3)*32 + (lane>>4)*8 + j.  Value = W[dout][k][t].
// Char frags at ws[0..49151], word frags at ws[49152..98303] (bf16 units).
// ---------------------------------------------------------------------------
__global__ void make_frags(const float* __restrict__ Wc,
                           const float* __restrict__ Ww,
                           unsigned short* __restrict__ out) {
    int i = blockIdx.x * 256 + threadIdx.x;            // 0..98303
    const int half = 12 * 8 * 64 * 8;                  // 49152
    const float* W = (i < half) ? Wc : Ww;
    int ii = (i < half) ? i : i - half;
    int j    = ii & 7;
    int lane = (ii >> 3) & 63;
    int nt   = (ii >> 9) & 7;
    int s    = ii >> 12;
    int dout = nt * 16 + (lane & 15);
    int t    = s >> 2;
    int k    = (s & 3) * 32 + ((lane >> 4) & 3) * 8 + j;
    out[i] = f2bf(W[(dout * 128 + k) * 3 + t]);
}

// ---------------------------------------------------------------------------
// Char path: one word per iteration; block = 128 thr (2 waves x 4 ntiles).
// A = im2col of 16 char-embedding rows (padded rows 0 and 17 = zero) in bf16.
// Y[c=16, dout=128] via MFMA, then max over c, +bias (fp32), write
// out1[b][dout][l] as fp32.
// ---------------------------------------------------------------------------
__global__ __launch_bounds__(128, 2) void char_kernel(
    const int* __restrict__ wic, const float* __restrict__ chrT,
    const unsigned short* __restrict__ frags,
    const float* __restrict__ bias,
    float* __restrict__ out1) {
    __shared__ unsigned short X[18 * 136];  // stride 136 => conflict-free b128
    const int tid  = threadIdx.x;
    const int wave = tid >> 6, lane = tid & 63;
    const int m = lane & 15, quad = lane >> 4;

    // zero pad rows (row 0 = c=-1, row 17 = c=16); never overwritten after
    for (int p = tid; p < 136; p += 128) { X[p] = 0; X[17 * 136 + p] = 0; }

    // resident B fragments: 12 k-steps x 4 ntiles (this wave's 64 douts)
    short8 bfrag[12][4];
#pragma unroll
    for (int s = 0; s < 12; ++s)
#pragma unroll
        for (int p = 0; p < 4; ++p) {
            int nt = wave * 4 + p;
            bfrag[s][p] =
                *(const short8*)(frags + (((s * 8 + nt) * 64 + lane) << 3));
        }
    float bb[4];
#pragma unroll
    for (int p = 0; p < 4; ++p) bb[p] = bias[wave * 64 + p * 16 + m];

    const int r = tid >> 3, seg = tid & 7;  // staging: 16 rows x 8 segs x 16 el
    for (int wl = 0; wl < 8; ++wl) {
        int w = blockIdx.x * 8 + wl;
        __syncthreads();  // previous iteration's reads done
        int idx = wic[w * 16 + r];
        const float4_t* src = (const float4_t*)(chrT + idx * 128 + seg * 16);
        unsigned short tmp[16];
#pragma unroll
        for (int q = 0; q < 4; ++q) {
            float4_t f = src[q];
            tmp[q * 4 + 0] = f2bf(f.x);
            tmp[q * 4 + 1] = f2bf(f.y);
            tmp[q * 4 + 2] = f2bf(f.z);
            tmp[q * 4 + 3] = f2bf(f.w);
        }
        *(short8*)&X[(r + 1) * 136 + seg * 16]     = *(const short8*)&tmp[0];
        *(short8*)&X[(r + 1) * 136 + seg * 16 + 8] = *(const short8*)&tmp[8];
        __syncthreads();

        float4_t acc[4];
#pragma unroll
        for (int p = 0; p < 4; ++p) acc[p] = (float4_t){0.f, 0.f, 0.f, 0.f};
#pragma unroll
        for (int s = 0; s < 12; ++s) {
            int row = m + (s >> 2);  // buffer row = c + t
            short8 a =
                *(const short8*)&X[row * 136 + (s & 3) * 32 + quad * 8];
#pragma unroll
            for (int p = 0; p < 4; ++p)
                acc[p] = __builtin_amdgcn_mfma_f32_16x16x32_bf16(
                    a, bfrag[s][p], acc[p], 0, 0, 0);
        }

        // epilogue: max over the 16 c-rows, +bias, write out1[b][dout][l]
        int b = w >> 8, l = w & 255;
        float* obase = out1 + b * (ND * NL) + l;
#pragma unroll
        for (int p = 0; p < 4; ++p) {
            float v = fmaxf(fmaxf(acc[p].x, acc[p].y),
                            fmaxf(acc[p].z, acc[p].w));
            v = fmaxf(v, __shfl_xor(v, 16, 64));
            v = fmaxf(v, __shfl_xor(v, 32, 64));
            v += bb[p];
            if (quad == 0) obase[(wave * 64 + p * 16 + m) * NL] = v;
        }
    }
}

// ---------------------------------------------------------------------------
// Word path: tiles of 16 consecutive l within one batch row. 18 staged rows
// (l0-1 .. l0+16); out-of-range l uses table row 0 (all zeros, padding_idx=0).
// Writes out0[b][dout][l0+row] with packed float4 stores.
// ---------------------------------------------------------------------------
__global__ __launch_bounds__(128, 2) void word_kernel(
    const int* __restrict__ wv, const float* __restrict__ wordT,
    const unsigned short* __restrict__ frags,
    const float* __restrict__ bias,
    float* __restrict__ out0) {
    __shared__ unsigned short X[18 * 136];
    const int tid  = threadIdx.x;
    const int wave = tid >> 6, lane = tid & 63;
    const int m = lane & 15, quad = lane >> 4;

    short8 bfrag[12][4];
#pragma unroll
    for (int s = 0; s < 12; ++s)
#pragma unroll
        for (int p = 0; p < 4; ++p) {
            int nt = wave * 4 + p;
            bfrag[s][p] = *(const short8*)(frags + 49152 +
                                           (((s * 8 + nt) * 64 + lane) << 3));
        }
    float bb[4];
#pragma unroll
    for (int p = 0; p < 4; ++p) bb[p] = bias[wave * 64 + p * 16 + m];

    for (int tl = 0; tl < 2; ++tl) {
        int tile = blockIdx.x * 2 + tl;
        int b = tile >> 4, l0 = (tile & 15) << 4;
        __syncthreads();
        for (int i = tid; i < 144; i += 128) {  // 18 rows x 8 segs
            int rr = i >> 3, sg = i & 7;
            int l = l0 + rr - 1;
            int idx = (l >= 0 && l < NL) ? wv[b * NL + l] : 0;  // row0 == zeros
            const float4_t* src = (const float4_t*)(wordT + idx * 128 + sg * 16);
            unsigned short tmp[16];
#pragma unroll
            for (int q = 0; q < 4; ++q) {
                float4_t f = src[q];
                tmp[q * 4 + 0] = f2bf(f.x);
                tmp[q * 4 + 1] = f2bf(f.y);
                tmp[q * 4 + 2] = f2bf(f.z);
                tmp[q * 4 + 3] = f2bf(f.w);
            }
            *(short8*)&X[rr * 136 + sg * 16]     = *(const short8*)&tmp[0];
            *(short8*)&X[rr * 136 + sg * 16 + 8] = *(const short8*)&tmp[8];
        }
        __syncthreads();

        float4_t acc[4];
#pragma unroll
        for (int p = 0; p < 4; ++p) acc[p] = (float4_t){0.f, 0.f, 0.f, 0.f};
#pragma unroll
        for (int s = 0; s < 12; ++s) {
            short8 a = *(const short8*)&X[(m + (s >> 2)) * 136 +
                                          (s & 3) * 32 + quad * 8];
#pragma unroll
            for (int p = 0; p < 4; ++p)
                acc[p] = __builtin_amdgcn_mfma_f32_16x16x32_bf16(
                    a, bfrag[s][p], acc[p], 0, 0, 0);
        }

        // D[row=l_local=quad*4+reg][col=dout_local=m]; pack 4 l's per lane
        float* obase = out0 + b * (ND * NL) + l0 + quad * 4;
#pragma unroll
        for (int p = 0; p < 4; ++p) {
            int dout = wave * 64 + p * 16 + m;
            float4_t pk;
            pk.x = acc[p].x + bb[p];
            pk.y = acc[p].y + bb[p];
            pk.z = acc[p].z + bb[p];
            pk.w = acc[p].w + bb[p];
            *(float4_t*)&obase[dout * NL] = pk;
        }
    }
}

extern "C" void kernel_launch(void* const* d_in, const int* in_sizes, int n_in,
                              void* d_out, int out_size, void* d_ws,
                              size_t ws_size, hipStream_t stream) {
    const int* word_vector   = (const int*)d_in[0];
    const int* words_in_char = (const int*)d_in[1];
    const float* word_table  = (const float*)d_in[2];
    const float* chr_table   = (const float*)d_in[3];
    const float* conv_chr_w  = (const float*)d_in[4];
    const float* conv_chr_b  = (const float*)d_in[5];
    const float* conv_word_w = (const float*)d_in[6];
    const float* conv_word_b = (const float*)d_in[7];
    float* out            = (float*)d_out;
    unsigned short* frags = (unsigned short*)d_ws;  // 98304 bf16 = 192 KB

    make_frags<<<384, 256, 0, stream>>>(conv_chr_w, conv_word_w, frags);
    char_kernel<<<1024, 128, 0, stream>>>(words_in_char, chr_table, frags,
                                          conv_chr_b, out + OUT_PLANE);
    word_kernel<<<256, 128, 0, stream>>>(word_vector, word_table, frags,
                                         conv_word_b, out);
}

// Round 3
// 106.221 us; speedup vs baseline: 1.0365x; 1.0365x over previous
//
#include <hip/hip_runtime.h>

typedef __attribute__((ext_vector_type(8))) short short8;
typedef __attribute__((ext_vector_type(4))) float float4_t;

#define NB 32
#define NL 256
#define ND 128
#define OUT_PLANE (NB * ND * NL)   // elements per stacked output plane
#define XS 136                     // LDS row stride (bf16 units): conflict-free

__device__ inline unsigned short f2bf(float f) {
    union { float f; unsigned int i; } c;
    c.f = f;
    unsigned int r = c.i + 0x7FFFu + ((c.i >> 16) & 1u);  // RN-even
    return (unsigned short)(r >> 16);
}

// ---------------------------------------------------------------------------
// Pre-permute fp32 conv weights [D,Din,3] into bf16 per-lane MFMA B-fragment
// order: frag[s][nt][lane][j].  B[k'][n]: n = lane&15, k' = s*32+(lane>>4)*8+j,
// tap t = s>>2, k = (s&3)*32 + (lane>>4)*8 + j.  Value = W[dout][k][t].
// Char frags at ws[0..49151], word frags at ws[49152..98303] (bf16 units).
// ---------------------------------------------------------------------------
__global__ void make_frags(const float* __restrict__ Wc,
                           const float* __restrict__ Ww,
                           unsigned short* __restrict__ out) {
    int i = blockIdx.x * 256 + threadIdx.x;            // 0..98303
    const int half = 12 * 8 * 64 * 8;                  // 49152
    const float* W = (i < half) ? Wc : Ww;
    int ii = (i < half) ? i : i - half;
    int j    = ii & 7;
    int lane = (ii >> 3) & 63;
    int nt   = (ii >> 9) & 7;
    int s    = ii >> 12;
    int dout = nt * 16 + (lane & 15);
    int t    = s >> 2;
    int k    = (s & 3) * 32 + ((lane >> 4) & 3) * 8 + j;
    out[i] = f2bf(W[(dout * 128 + k) * 3 + t]);
}

// ---------------------------------------------------------------------------
// Merged conv kernel. Blocks 0..511: word path (1 tile of 16 l each).
// Blocks 512..1535: char path (8 words each, double-buffered pipeline).
// Block = 128 thr = 2 waves; wave w covers douts [w*64, w*64+64).
// ---------------------------------------------------------------------------
__global__ __launch_bounds__(128, 2) void conv_kernel(
    const int* __restrict__ wv, const int* __restrict__ wic,
    const float* __restrict__ wordT, const float* __restrict__ chrT,
    const unsigned short* __restrict__ frags,
    const float* __restrict__ biasC, const float* __restrict__ biasW,
    float* __restrict__ out) {
    __shared__ unsigned short X[2][18 * XS];
    const int tid  = threadIdx.x;
    const int wave = tid >> 6, lane = tid & 63;
    const int m = lane & 15, quad = lane >> 4;
    const int bid = blockIdx.x;

    if (bid >= 512) {
        // ------------------------- char path -------------------------------
        const int w0 = (bid - 512) * 8;
        short8 bfrag[12][4];
#pragma unroll
        for (int s = 0; s < 12; ++s)
#pragma unroll
            for (int p = 0; p < 4; ++p)
                bfrag[s][p] = *(const short8*)(
                    frags + (((s * 8 + wave * 4 + p) * 64 + lane) << 3));
        float bb[4];
#pragma unroll
        for (int p = 0; p < 4; ++p) bb[p] = biasC[wave * 64 + p * 16 + m];

        // zero pad rows (c=-1 and c=16) in both buffers; never overwritten
        for (int p = tid; p < XS; p += 128) {
            X[0][p] = 0; X[0][17 * XS + p] = 0;
            X[1][p] = 0; X[1][17 * XS + p] = 0;
        }
        const int r = tid >> 3, seg = tid & 7;  // 16 rows x 8 segs of 16 el

        // prologue: stage word 0 into X[0]; prefetch idx of word 1
        {
            int idx0 = wic[w0 * 16 + r];
            const float4_t* src = (const float4_t*)(chrT + idx0 * 128 + seg * 16);
            float4_t f0 = src[0], f1 = src[1], f2 = src[2], f3 = src[3];
            unsigned short t16[16];
            t16[0]=f2bf(f0.x); t16[1]=f2bf(f0.y); t16[2]=f2bf(f0.z); t16[3]=f2bf(f0.w);
            t16[4]=f2bf(f1.x); t16[5]=f2bf(f1.y); t16[6]=f2bf(f1.z); t16[7]=f2bf(f1.w);
            t16[8]=f2bf(f2.x); t16[9]=f2bf(f2.y); t16[10]=f2bf(f2.z); t16[11]=f2bf(f2.w);
            t16[12]=f2bf(f3.x); t16[13]=f2bf(f3.y); t16[14]=f2bf(f3.z); t16[15]=f2bf(f3.w);
            *(short8*)&X[0][(r + 1) * XS + seg * 16]     = *(const short8*)&t16[0];
            *(short8*)&X[0][(r + 1) * XS + seg * 16 + 8] = *(const short8*)&t16[8];
        }
        int idxA = wic[(w0 + 1) * 16 + r];
        __syncthreads();

#pragma unroll
        for (int wl = 0; wl < 8; ++wl) {
            const int cur = wl & 1;
            // issue next word's gather early (hidden under MFMA)
            float4_t f0, f1, f2, f3;
            if (wl < 7) {
                const float4_t* src =
                    (const float4_t*)(chrT + idxA * 128 + seg * 16);
                f0 = src[0]; f1 = src[1]; f2 = src[2]; f3 = src[3];
            }
            int idxB = (wl < 6) ? wic[(w0 + wl + 2) * 16 + r] : 0;

            float4_t acc[4];
#pragma unroll
            for (int p = 0; p < 4; ++p) acc[p] = (float4_t){0.f, 0.f, 0.f, 0.f};
#pragma unroll
            for (int s = 0; s < 12; ++s) {
                short8 a = *(const short8*)&X[cur][(m + (s >> 2)) * XS +
                                                  (s & 3) * 32 + quad * 8];
#pragma unroll
                for (int p = 0; p < 4; ++p)
                    acc[p] = __builtin_amdgcn_mfma_f32_16x16x32_bf16(
                        a, bfrag[s][p], acc[p], 0, 0, 0);
            }

            if (wl < 7) {  // write next buffer (prev readers of it are done)
                unsigned short t16[16];
                t16[0]=f2bf(f0.x); t16[1]=f2bf(f0.y); t16[2]=f2bf(f0.z); t16[3]=f2bf(f0.w);
                t16[4]=f2bf(f1.x); t16[5]=f2bf(f1.y); t16[6]=f2bf(f1.z); t16[7]=f2bf(f1.w);
                t16[8]=f2bf(f2.x); t16[9]=f2bf(f2.y); t16[10]=f2bf(f2.z); t16[11]=f2bf(f2.w);
                t16[12]=f2bf(f3.x); t16[13]=f2bf(f3.y); t16[14]=f2bf(f3.z); t16[15]=f2bf(f3.w);
                *(short8*)&X[cur ^ 1][(r + 1) * XS + seg * 16]     = *(const short8*)&t16[0];
                *(short8*)&X[cur ^ 1][(r + 1) * XS + seg * 16 + 8] = *(const short8*)&t16[8];
                idxA = idxB;
            }
            __syncthreads();

            // epilogue: max over 16 c-rows, +bias, scalar store out1[b][dout][l]
            int w = w0 + wl, b = w >> 8, l = w & 255;
            float* obase = out + OUT_PLANE + b * (ND * NL) + l;
#pragma unroll
            for (int p = 0; p < 4; ++p) {
                float v = fmaxf(fmaxf(acc[p].x, acc[p].y),
                                fmaxf(acc[p].z, acc[p].w));
                v = fmaxf(v, __shfl_xor(v, 16, 64));
                v = fmaxf(v, __shfl_xor(v, 32, 64));
                v += bb[p];
                if (quad == 0) obase[(wave * 64 + p * 16 + m) * NL] = v;
            }
        }
    } else {
        // ------------------------- word path -------------------------------
        const int b = bid >> 4, l0 = (bid & 15) << 4;
        short8 bfrag[12][4];
#pragma unroll
        for (int s = 0; s < 12; ++s)
#pragma unroll
            for (int p = 0; p < 4; ++p)
                bfrag[s][p] = *(const short8*)(
                    frags + 49152 + (((s * 8 + wave * 4 + p) * 64 + lane) << 3));
        float bb[4];
#pragma unroll
        for (int p = 0; p < 4; ++p) bb[p] = biasW[wave * 64 + p * 16 + m];

#pragma unroll
        for (int i0 = 0; i0 < 2; ++i0) {   // 18 rows x 8 segs = 144 jobs
            int i = tid + i0 * 128;
            if (i < 144) {
                int rr = i >> 3, sg = i & 7;
                int l = l0 + rr - 1;
                int idx = (l >= 0 && l < NL) ? wv[b * NL + l] : 0;  // row0 = zeros
                const float4_t* src =
                    (const float4_t*)(wordT + idx * 128 + sg * 16);
                float4_t f0 = src[0], f1 = src[1], f2 = src[2], f3 = src[3];
                unsigned short t16[16];
                t16[0]=f2bf(f0.x); t16[1]=f2bf(f0.y); t16[2]=f2bf(f0.z); t16[3]=f2bf(f0.w);
                t16[4]=f2bf(f1.x); t16[5]=f2bf(f1.y); t16[6]=f2bf(f1.z); t16[7]=f2bf(f1.w);
                t16[8]=f2bf(f2.x); t16[9]=f2bf(f2.y); t16[10]=f2bf(f2.z); t16[11]=f2bf(f2.w);
                t16[12]=f2bf(f3.x); t16[13]=f2bf(f3.y); t16[14]=f2bf(f3.z); t16[15]=f2bf(f3.w);
                *(short8*)&X[0][rr * XS + sg * 16]     = *(const short8*)&t16[0];
                *(short8*)&X[0][rr * XS + sg * 16 + 8] = *(const short8*)&t16[8];
            }
        }
        __syncthreads();

        float4_t acc[4];
#pragma unroll
        for (int p = 0; p < 4; ++p) acc[p] = (float4_t){0.f, 0.f, 0.f, 0.f};
#pragma unroll
        for (int s = 0; s < 12; ++s) {
            short8 a = *(const short8*)&X[0][(m + (s >> 2)) * XS +
                                            (s & 3) * 32 + quad * 8];
#pragma unroll
            for (int p = 0; p < 4; ++p)
                acc[p] = __builtin_amdgcn_mfma_f32_16x16x32_bf16(
                    a, bfrag[s][p], acc[p], 0, 0, 0);
        }

        // D[row = l_local = quad*4+reg][col = dout_local = m]; 4 l's per lane
        float* obase = out + b * (ND * NL) + l0 + quad * 4;
#pragma unroll
        for (int p = 0; p < 4; ++p) {
            int dout = wave * 64 + p * 16 + m;
            float4_t pk;
            pk.x = acc[p].x + bb[p];
            pk.y = acc[p].y + bb[p];
            pk.z = acc[p].z + bb[p];
            pk.w = acc[p].w + bb[p];
            *(float4_t*)&obase[dout * NL] = pk;
        }
    }
}

extern "C" void kernel_launch(void* const* d_in, const int* in_sizes, int n_in,
                              void* d_out, int out_size, void* d_ws,
                              size_t ws_size, hipStream_t stream) {
    const int* word_vector   = (const int*)d_in[0];
    const int* words_in_char = (const int*)d_in[1];
    const float* word_table  = (const float*)d_in[2];
    const float* chr_table   = (const float*)d_in[3];
    const float* conv_chr_w  = (const float*)d_in[4];
    const float* conv_chr_b  = (const float*)d_in[5];
    const float* conv_word_w = (const float*)d_in[6];
    const float* conv_word_b = (const float*)d_in[7];
    float* out            = (float*)d_out;
    unsigned short* frags = (unsigned short*)d_ws;  // 98304 bf16 = 192 KB

    make_frags<<<384, 256, 0, stream>>>(conv_chr_w, conv_word_w, frags);
    conv_kernel<<<1536, 128, 0, stream>>>(word_vector, words_in_char,
                                          word_table, chr_table, frags,
                                          conv_chr_b, conv_word_b, out);
}